// Round 1
// baseline (66.322 us; speedup 1.0000x reference)
//
#include <hip/hip_runtime.h>
#include <math.h>

#define ACC_LIMIT 3.0f
#define STEER_LIMIT 0.6f
#define V_MIN 0.0f
#define V_MAX 30.0f
#define L_INV (1.0f / 2.7f)
#define HLEN 8192
#define NT 1024
#define EPT 8   // elements per thread: HLEN / NT

// Representation of f(v) = clamp(v + s, lo, hi). Closed under composition.
struct Cl { float s, lo, hi; };

// p applied FIRST, then q.  q(p(v)) = clamp(v + (p.s+q.s), max(p.lo+q.s, q.lo),
//                                          min(max(p.hi+q.s, q.lo), q.hi))
__device__ __forceinline__ Cl comp(Cl p, Cl q) {
    Cl r;
    r.s  = p.s + q.s;
    r.lo = fmaxf(p.lo + q.s, q.lo);
    r.hi = fminf(fmaxf(p.hi + q.s, q.lo), q.hi);
    return r;
}
__device__ __forceinline__ float applyCl(Cl f, float v) {
    return fminf(fmaxf(v + f.s, f.lo), f.hi);
}

__global__ __launch_bounds__(NT)
void KinematicBicycle_kernel(const float* __restrict__ x0,
                             const float* __restrict__ U,
                             const float* __restrict__ dtp,
                             float* __restrict__ out) {
    const int tid  = threadIdx.x;
    const int lane = tid & 63;
    const int wid  = tid >> 6;   // 16 waves
    const float dt = dtp[0];

    __shared__ float s_cl[16 * 3];   // Cl partials per wave
    __shared__ float s_f[16];        // float scan partials
    __shared__ float s_f2[16 * 2];   // float2 scan partials

    // ---- load this thread's 8 control inputs (coalesced float2) ----
    const int base = tid * EPT;
    float a[EPT], dl[EPT];
    #pragma unroll
    for (int e = 0; e < EPT; e++) {
        float2 u = ((const float2*)U)[base + e];
        a[e]  = fminf(fmaxf(u.x, -ACC_LIMIT), ACC_LIMIT) * dt;   // pre-scaled a*dt
        dl[e] = fminf(fmaxf(u.y, -STEER_LIMIT), STEER_LIMIT);
    }

    // ================= Phase 1: velocity scan (clamped-add compositions) ====
    Cl loc = {0.f, -INFINITY, INFINITY};
    #pragma unroll
    for (int e = 0; e < EPT; e++) {
        Cl g = {a[e], V_MIN, V_MAX};
        loc = comp(loc, g);          // earlier applied first
    }
    // wave-level inclusive scan (Hillis-Steele, noncommutative-safe)
    Cl incl = loc;
    #pragma unroll
    for (int d = 1; d < 64; d <<= 1) {
        Cl o;
        o.s  = __shfl_up(incl.s,  d, 64);
        o.lo = __shfl_up(incl.lo, d, 64);
        o.hi = __shfl_up(incl.hi, d, 64);
        if (lane >= d) incl = comp(o, incl);
    }
    if (lane == 63) { s_cl[wid*3] = incl.s; s_cl[wid*3+1] = incl.lo; s_cl[wid*3+2] = incl.hi; }
    __syncthreads();
    if (tid == 0) {
        Cl run = {0.f, -INFINITY, INFINITY};
        for (int i = 0; i < 16; i++) {
            Cl t = {s_cl[i*3], s_cl[i*3+1], s_cl[i*3+2]};
            s_cl[i*3] = run.s; s_cl[i*3+1] = run.lo; s_cl[i*3+2] = run.hi;
            run = comp(run, t);
        }
    }
    __syncthreads();
    Cl wpre = {s_cl[wid*3], s_cl[wid*3+1], s_cl[wid*3+2]};
    Cl lpre;
    lpre.s  = __shfl_up(incl.s,  1, 64);
    lpre.lo = __shfl_up(incl.lo, 1, 64);
    lpre.hi = __shfl_up(incl.hi, 1, 64);
    if (lane == 0) { lpre.s = 0.f; lpre.lo = -INFINITY; lpre.hi = INFINITY; }
    Cl tpre = comp(wpre, lpre);      // everything before this thread

    const float v0c = fminf(fmaxf(x0[3], V_MIN), V_MAX);
    float v = applyCl(tpre, v0c);
    float vc[EPT + 1];               // vc[e] = v at time base+e (pre-step); vc[e+1] = post-step
    #pragma unroll
    for (int e = 0; e < EPT; e++) {
        vc[e] = v;
        v = fminf(fmaxf(v + a[e], V_MIN), V_MAX);
    }
    vc[EPT] = v;

    // ================= Phase 2: heading prefix sum =========================
    const float k = dt * L_INV;
    float w[EPT];
    float lsum = 0.f;
    #pragma unroll
    for (int e = 0; e < EPT; e++) {
        w[e] = vc[e] * tanf(dl[e]) * k;
        lsum += w[e];
    }
    float fincl = lsum;
    #pragma unroll
    for (int d = 1; d < 64; d <<= 1) {
        float o = __shfl_up(fincl, d, 64);
        if (lane >= d) fincl += o;
    }
    if (lane == 63) s_f[wid] = fincl;
    __syncthreads();
    if (tid == 0) {
        float run = 0.f;
        for (int i = 0; i < 16; i++) { float t = s_f[i]; s_f[i] = run; run += t; }
    }
    __syncthreads();
    float flpre = __shfl_up(fincl, 1, 64);
    if (lane == 0) flpre = 0.f;
    float th = x0[2] + s_f[wid] + flpre;   // theta at time base (pre-step)
    float tha[EPT];
    #pragma unroll
    for (int e = 0; e < EPT; e++) {
        tha[e] = th;
        th += w[e];
    }

    // ================= Phase 3: position prefix sums (x,y jointly) =========
    float cx[EPT], sy[EPT];
    float sx = 0.f, ss = 0.f;
    #pragma unroll
    for (int e = 0; e < EPT; e++) {
        float sn, cs;
        sincosf(tha[e], &sn, &cs);
        cx[e] = vc[e] * cs * dt;
        sy[e] = vc[e] * sn * dt;
        sx += cx[e];
        ss += sy[e];
    }
    float ix = sx, iy = ss;
    #pragma unroll
    for (int d = 1; d < 64; d <<= 1) {
        float ox = __shfl_up(ix, d, 64);
        float oy = __shfl_up(iy, d, 64);
        if (lane >= d) { ix += ox; iy += oy; }
    }
    if (lane == 63) { s_f2[wid*2] = ix; s_f2[wid*2+1] = iy; }
    __syncthreads();
    if (tid == 0) {
        float rx = 0.f, ry = 0.f;
        for (int i = 0; i < 16; i++) {
            float txv = s_f2[i*2], tyv = s_f2[i*2+1];
            s_f2[i*2] = rx; s_f2[i*2+1] = ry;
            rx += txv; ry += tyv;
        }
    }
    __syncthreads();
    float plx = __shfl_up(ix, 1, 64);
    float ply = __shfl_up(iy, 1, 64);
    if (lane == 0) { plx = 0.f; ply = 0.f; }
    float pxr = x0[0] + s_f2[wid*2]     + plx;   // x position at time base (pre-step)
    float pyr = x0[1] + s_f2[wid*2 + 1] + ply;

    // ================= Output ==============================================
    float4* out4 = (float4*)out;
    #pragma unroll
    for (int e = 0; e < EPT; e++) {
        pxr += cx[e];
        pyr += sy[e];
        float thout = tha[e] + w[e];
        float vout  = vc[e + 1];
        out4[base + e + 1] = make_float4(pxr, pyr, thout, vout);
    }
    if (tid == 0) out4[0] = make_float4(x0[0], x0[1], x0[2], x0[3]);
}

extern "C" void kernel_launch(void* const* d_in, const int* in_sizes, int n_in,
                              void* d_out, int out_size, void* d_ws, size_t ws_size,
                              hipStream_t stream) {
    const float* x0  = (const float*)d_in[0];
    const float* U   = (const float*)d_in[1];
    const float* dtp = (const float*)d_in[2];
    float* out = (float*)d_out;
    KinematicBicycle_kernel<<<1, NT, 0, stream>>>(x0, U, dtp, out);
}

// Round 2
// 63.500 us; speedup vs baseline: 1.0444x; 1.0444x over previous
//
#include <hip/hip_runtime.h>
#include <math.h>

#define ACC_LIMIT 3.0f
#define STEER_LIMIT 0.6f
#define V_MIN 0.0f
#define V_MAX 30.0f
#define L_INV (1.0f / 2.7f)
#define HLEN 8192
#define NT 1024
#define EPT 8   // elements per thread: HLEN / NT

// Representation of f(v) = clamp(v + s, lo, hi). Closed under composition.
struct Cl { float s, lo, hi; };

// p applied FIRST, then q.
__device__ __forceinline__ Cl comp(Cl p, Cl q) {
    Cl r;
    r.s  = p.s + q.s;
    r.lo = fmaxf(p.lo + q.s, q.lo);
    r.hi = fminf(fmaxf(p.hi + q.s, q.lo), q.hi);
    return r;
}
__device__ __forceinline__ float applyCl(Cl f, float v) {
    return fminf(fmaxf(v + f.s, f.lo), f.hi);
}

// tan(x) for |x| <= 0.6 : odd Taylor through x^15, rel err ~1.5e-7.
// No branches, no range reduction (delta is pre-clamped to [-0.6,0.6]).
__device__ __forceinline__ float tan06(float x) {
    float x2 = x * x;
    float p = 0.0014558344f;          // x^15
    p = fmaf(p, x2, 0.0035924222f);   // x^13
    p = fmaf(p, x2, 0.0088632355f);   // x^11
    p = fmaf(p, x2, 0.021869488f);    // x^9
    p = fmaf(p, x2, 0.05396825f);     // x^7
    p = fmaf(p, x2, 0.13333334f);     // x^5
    p = fmaf(p, x2, 0.33333334f);     // x^3
    p = fmaf(p, x2, 1.0f);
    return x * p;
}

__global__ __launch_bounds__(NT)
void KinematicBicycle_kernel(const float* __restrict__ x0,
                             const float* __restrict__ U,
                             const float* __restrict__ dtp,
                             float* __restrict__ out) {
    const int tid  = threadIdx.x;
    const int lane = tid & 63;
    const int wid  = tid >> 6;   // 16 waves
    const float dt = dtp[0];

    __shared__ float s_cl[16 * 3];
    __shared__ float s_f[16];
    __shared__ float s_f2[16 * 2];

    // ---- load 8 control inputs as 4x float4 (2 steps per load) ----
    const int base = tid * EPT;
    const float4* U4 = (const float4*)U;
    float a[EPT], tv[EPT];
    #pragma unroll
    for (int q = 0; q < 4; q++) {
        float4 u = U4[tid * 4 + q];
        a[2*q]    = fminf(fmaxf(u.x, -ACC_LIMIT), ACC_LIMIT) * dt;
        tv[2*q]   = tan06(fminf(fmaxf(u.y, -STEER_LIMIT), STEER_LIMIT));
        a[2*q+1]  = fminf(fmaxf(u.z, -ACC_LIMIT), ACC_LIMIT) * dt;
        tv[2*q+1] = tan06(fminf(fmaxf(u.w, -STEER_LIMIT), STEER_LIMIT));
    }

    // ================= Phase 1: velocity scan (clamped-add compositions) ====
    Cl loc = {0.f, -INFINITY, INFINITY};
    #pragma unroll
    for (int e = 0; e < EPT; e++) {
        Cl g = {a[e], V_MIN, V_MAX};
        loc = comp(loc, g);
    }
    Cl incl = loc;
    #pragma unroll
    for (int d = 1; d < 64; d <<= 1) {
        Cl o;
        o.s  = __shfl_up(incl.s,  d, 64);
        o.lo = __shfl_up(incl.lo, d, 64);
        o.hi = __shfl_up(incl.hi, d, 64);
        if (lane >= d) incl = comp(o, incl);
    }
    if (lane == 63) { s_cl[wid*3] = incl.s; s_cl[wid*3+1] = incl.lo; s_cl[wid*3+2] = incl.hi; }
    __syncthreads();
    if (tid == 0) {
        Cl run = {0.f, -INFINITY, INFINITY};
        for (int i = 0; i < 16; i++) {
            Cl t = {s_cl[i*3], s_cl[i*3+1], s_cl[i*3+2]};
            s_cl[i*3] = run.s; s_cl[i*3+1] = run.lo; s_cl[i*3+2] = run.hi;
            run = comp(run, t);
        }
    }
    __syncthreads();
    Cl wpre = {s_cl[wid*3], s_cl[wid*3+1], s_cl[wid*3+2]};
    Cl lpre;
    lpre.s  = __shfl_up(incl.s,  1, 64);
    lpre.lo = __shfl_up(incl.lo, 1, 64);
    lpre.hi = __shfl_up(incl.hi, 1, 64);
    if (lane == 0) { lpre.s = 0.f; lpre.lo = -INFINITY; lpre.hi = INFINITY; }
    Cl tpre = comp(wpre, lpre);

    const float v0c = fminf(fmaxf(x0[3], V_MIN), V_MAX);
    float v = applyCl(tpre, v0c);
    float vc[EPT + 1];
    #pragma unroll
    for (int e = 0; e < EPT; e++) {
        vc[e] = v;
        v = fminf(fmaxf(v + a[e], V_MIN), V_MAX);
    }
    vc[EPT] = v;

    // ================= Phase 2: heading prefix sum =========================
    const float k = dt * L_INV;
    float w[EPT];
    float lsum = 0.f;
    #pragma unroll
    for (int e = 0; e < EPT; e++) {
        w[e] = vc[e] * tv[e] * k;
        lsum += w[e];
    }
    float fincl = lsum;
    #pragma unroll
    for (int d = 1; d < 64; d <<= 1) {
        float o = __shfl_up(fincl, d, 64);
        if (lane >= d) fincl += o;
    }
    if (lane == 63) s_f[wid] = fincl;
    __syncthreads();
    if (tid == 0) {
        float run = 0.f;
        for (int i = 0; i < 16; i++) { float t = s_f[i]; s_f[i] = run; run += t; }
    }
    __syncthreads();
    float flpre = __shfl_up(fincl, 1, 64);
    if (lane == 0) flpre = 0.f;
    float th = x0[2] + s_f[wid] + flpre;
    float tha[EPT];
    #pragma unroll
    for (int e = 0; e < EPT; e++) {
        tha[e] = th;
        th += w[e];
    }

    // ================= Phase 3: position prefix sums =======================
    float cx[EPT], sy[EPT];
    float sx = 0.f, ss = 0.f;
    #pragma unroll
    for (int e = 0; e < EPT; e++) {
        float sn = __sinf(tha[e]);     // v_sin_f32 (theta bounded: tens of rad)
        float cs = __cosf(tha[e]);     // v_cos_f32
        cx[e] = vc[e] * cs * dt;
        sy[e] = vc[e] * sn * dt;
        sx += cx[e];
        ss += sy[e];
    }
    float ix = sx, iy = ss;
    #pragma unroll
    for (int d = 1; d < 64; d <<= 1) {
        float ox = __shfl_up(ix, d, 64);
        float oy = __shfl_up(iy, d, 64);
        if (lane >= d) { ix += ox; iy += oy; }
    }
    if (lane == 63) { s_f2[wid*2] = ix; s_f2[wid*2+1] = iy; }
    __syncthreads();
    if (tid == 0) {
        float rx = 0.f, ry = 0.f;
        for (int i = 0; i < 16; i++) {
            float txv = s_f2[i*2], tyv = s_f2[i*2+1];
            s_f2[i*2] = rx; s_f2[i*2+1] = ry;
            rx += txv; ry += tyv;
        }
    }
    __syncthreads();
    float plx = __shfl_up(ix, 1, 64);
    float ply = __shfl_up(iy, 1, 64);
    if (lane == 0) { plx = 0.f; ply = 0.f; }
    float pxr = x0[0] + s_f2[wid*2]     + plx;
    float pyr = x0[1] + s_f2[wid*2 + 1] + ply;

    // ================= Output ==============================================
    float4* out4 = (float4*)out;
    #pragma unroll
    for (int e = 0; e < EPT; e++) {
        pxr += cx[e];
        pyr += sy[e];
        float thout = tha[e] + w[e];
        float vout  = vc[e + 1];
        out4[base + e + 1] = make_float4(pxr, pyr, thout, vout);
    }
    if (tid == 0) out4[0] = make_float4(x0[0], x0[1], x0[2], x0[3]);
}

extern "C" void kernel_launch(void* const* d_in, const int* in_sizes, int n_in,
                              void* d_out, int out_size, void* d_ws, size_t ws_size,
                              hipStream_t stream) {
    const float* x0  = (const float*)d_in[0];
    const float* U   = (const float*)d_in[1];
    const float* dtp = (const float*)d_in[2];
    float* out = (float*)d_out;
    KinematicBicycle_kernel<<<1, NT, 0, stream>>>(x0, U, dtp, out);
}